// Round 1
// baseline (467.334 us; speedup 1.0000x reference)
//
#include <hip/hip_runtime.h>
#include <hip/hip_bf16.h>

// Problem constants: x is (N=16, C=64, H=512, W=512) float32, LEVEL_NUM=16.
#define NB   16
#define CB   64
#define HH   512
#define WW   512
#define HWP  (HH*WW)          // 262144 pixels per (n,c)
#define LEV  16

typedef __attribute__((ext_vector_type(8))) short short8;
typedef __attribute__((ext_vector_type(4))) float f32x4;

// ---- helpers -------------------------------------------------------------

__device__ inline float wred_sum(float v){
  #pragma unroll
  for (int m = 32; m > 0; m >>= 1) v += __shfl_xor(v, m, 64);
  return v;
}
__device__ inline float wred_min(float v){
  #pragma unroll
  for (int m = 32; m > 0; m >>= 1) v = fminf(v, __shfl_xor(v, m, 64));
  return v;
}
__device__ inline float wred_max(float v){
  #pragma unroll
  for (int m = 32; m > 0; m >>= 1) v = fmaxf(v, __shfl_xor(v, m, 64));
  return v;
}

// monotonic float<->uint mapping so we can use atomicMin/Max on unsigned
__device__ inline unsigned fl(float f){
  unsigned b = __float_as_uint(f);
  return (b & 0x80000000u) ? ~b : (b | 0x80000000u);
}
__device__ inline float unfl(unsigned u){
  unsigned b = (u & 0x80000000u) ? (u ^ 0x80000000u) : ~u;
  return __uint_as_float(b);
}

// f32 -> bf16 bits, round-to-nearest-even (no NaN inputs here)
__device__ inline unsigned short f2bf(float f){
  unsigned u = __float_as_uint(f);
  unsigned r = (u + 0x7fffu + ((u >> 16) & 1u)) >> 16;
  return (unsigned short)r;
}

// ---- ws layout (float offsets) ------------------------------------------
// [0,1024)      sumc   per-(n,c) channel sums
// [1024,2048)   a_norm normalized x_ave
// [2048,2064)   umin (uint, flipped)
// [2064,2080)   umax (uint, flipped)
// [2080,6176)   sta accumulators (16 x 256)
// [8192, 8192+16*262144)  cos_sim
#define WS_SUMC 0
#define WS_AN   1024
#define WS_MIN  2048
#define WS_MAX  2064
#define WS_STA  2080
#define WS_COS  8192

// ---- K0: init accumulators ----------------------------------------------
__global__ void k0_init(float* ws){
  int idx = blockIdx.x * 256 + threadIdx.x;   // grid 16x256 = 4096
  if (idx < 1024) ws[WS_SUMC + idx] = 0.0f;
  unsigned* u = (unsigned*)ws;
  if (idx < 16){ u[WS_MIN + idx] = 0xFFFFFFFFu; u[WS_MAX + idx] = 0u; }
  if (idx < 4096) ws[WS_STA + idx] = 0.0f;
}

// ---- K1: per-(n,c) sums over H*W  (reads x once: 1 GiB) -----------------
__global__ void __launch_bounds__(256) k1_sums(const float4* __restrict__ xv,
                                               float* __restrict__ sumc){
  int bid = blockIdx.x;              // grid = 1024*16 = 16384
  int nc = bid >> 4, seg = bid & 15;
  int t = threadIdx.x;
  const float4* xb = xv + (size_t)nc * (HWP/4) + (size_t)seg * 4096;
  float s = 0.0f;
  #pragma unroll
  for (int k = 0; k < 16; ++k){
    float4 v = xb[k*256 + t];
    s += (v.x + v.y) + (v.z + v.w);
  }
  s = wred_sum(s);
  __shared__ float sm[4];
  if ((t & 63) == 0) sm[t >> 6] = s;
  __syncthreads();
  if (t == 0) atomicAdd(&sumc[nc], (sm[0]+sm[1])+(sm[2]+sm[3]));
}

// ---- K1b: normalize x_ave (one wave per n) ------------------------------
__global__ void __launch_bounds__(1024) k1b_norm(const float* __restrict__ sumc,
                                                 float* __restrict__ an){
  int t = threadIdx.x;               // 1 block x 1024; wave = one n
  float val = sumc[t] * (1.0f / (float)HWP);   // mean
  float s2 = wred_sum(val * val);
  float rn = 1.0f / fmaxf(sqrtf(s2), 1e-12f);
  an[t] = val * rn;
}

// ---- K2: cosine map + per-n min/max  (reads x again: 1 GiB) -------------
__global__ void __launch_bounds__(256) k2_cos(const float4* __restrict__ xv,
                                              const float* __restrict__ an,
                                              float4* __restrict__ cosv,
                                              unsigned* __restrict__ mn,
                                              unsigned* __restrict__ mx){
  int bid = blockIdx.x;              // grid = 16*256 = 4096
  int n = bid >> 8, chunk = bid & 255;
  int t = threadIdx.x;
  __shared__ float sa[CB];
  if (t < CB) sa[t] = an[n*CB + t];
  __syncthreads();

  int pv = chunk*256 + t;            // float4 index within this n's pixels
  const float4* xb = xv + (size_t)n * CB * (HWP/4) + pv;
  float4 dot = make_float4(0,0,0,0), nrm = make_float4(0,0,0,0);
  #pragma unroll 8
  for (int c = 0; c < CB; ++c){
    float4 v = xb[(size_t)c * (HWP/4)];
    float a = sa[c];
    dot.x += a*v.x; dot.y += a*v.y; dot.z += a*v.z; dot.w += a*v.w;
    nrm.x += v.x*v.x; nrm.y += v.y*v.y; nrm.z += v.z*v.z; nrm.w += v.w*v.w;
  }
  float4 cs;
  cs.x = dot.x / fmaxf(sqrtf(nrm.x), 1e-12f);
  cs.y = dot.y / fmaxf(sqrtf(nrm.y), 1e-12f);
  cs.z = dot.z / fmaxf(sqrtf(nrm.z), 1e-12f);
  cs.w = dot.w / fmaxf(sqrtf(nrm.w), 1e-12f);
  cosv[(size_t)n * (HWP/4) + pv] = cs;

  float mnl = fminf(fminf(cs.x, cs.y), fminf(cs.z, cs.w));
  float mxl = fmaxf(fmaxf(cs.x, cs.y), fmaxf(cs.z, cs.w));
  mnl = wred_min(mnl); mxl = wred_max(mxl);
  __shared__ float smn[4], smx[4];
  if ((t & 63) == 0){ smn[t >> 6] = mnl; smx[t >> 6] = mxl; }
  __syncthreads();
  if (t == 0){
    float m0 = fminf(fminf(smn[0], smn[1]), fminf(smn[2], smn[3]));
    float M0 = fmaxf(fmaxf(smx[0], smx[1]), fmaxf(smx[2], smx[3]));
    atomicMin(&mn[n], fl(m0));
    atomicMax(&mx[n], fl(M0));
  }
}

// ---- K4: soft-quant + co-occurrence via MFMA ----------------------------
// Each wave owns one row-pair (h, h+1) and accumulates the full 16x16 sta
// tile over the 511 valid w positions:  sta[i][j] += A[i][px] * B[px][j]
// A = quant levels of row h at pixel px, B = quant of row h+1 at px+1.
// Fragment fill uses level = lane%16, k = (lane/16)*8+e for BOTH operands;
// correctness only needs A/B to use the same pixel for the same k.
__global__ void __launch_bounds__(256) k4_sta(const float* __restrict__ cosb,
                                              const unsigned* __restrict__ mn,
                                              const unsigned* __restrict__ mx,
                                              float* __restrict__ sta){
  int bid = blockIdx.x;              // grid = 16*128 = 2048, 4 waves/block
  int n = bid >> 7, pb = bid & 127;
  int t = threadIdx.x;
  int wv = t >> 6, lane = t & 63;
  int h = pb*4 + wv;
  if (h > HH - 2) return;            // valid row pairs: h in [0,510]

  int lvl = lane & 15, g = lane >> 4;
  float cmin = unfl(mn[n]), cmax = unfl(mx[n]);
  float q = (float)(2*lvl + 1) * (1.0f/32.0f) * (cmax - cmin) + cmin;

  const float* rowA = cosb + (size_t)n * HWP + (size_t)h * WW;
  const float* rowB = rowA + WW;
  const float c3 = -0.022542110013890053f;   // -(sigma^2)*log2(e), sigma^2=1/64

  f32x4 acc = {0.f, 0.f, 0.f, 0.f};
  #pragma unroll 4
  for (int kc = 0; kc < 16; ++kc){
    int px = kc*32 + g*8;
    float4 a0 = *(const float4*)(rowA + px);
    float4 a1 = *(const float4*)(rowA + px + 4);
    float4 b0 = *(const float4*)(rowB + px);
    float4 b1 = *(const float4*)(rowB + px + 4);
    float b8 = (px + 8 <= WW - 1) ? rowB[px + 8] : 0.0f;
    float av[8] = {a0.x,a0.y,a0.z,a0.w,a1.x,a1.y,a1.z,a1.w};
    float bv[8] = {b0.y,b0.z,b0.w,b1.x,b1.y,b1.z,b1.w,b8};
    short8 af, bf;
    #pragma unroll
    for (int e = 0; e < 8; ++e){
      float da = av[e] - q;  float pa = exp2f(c3*da*da);
      float db = bv[e] - q;  float pbv = exp2f(c3*db*db);
      if (px + e > WW - 2){ pa = 0.0f; pbv = 0.0f; }   // zero-pad border w=511
      af[e] = (short)f2bf(pa);
      bf[e] = (short)f2bf(pbv);
    }
    acc = __builtin_amdgcn_mfma_f32_16x16x32_bf16(af, bf, acc, 0, 0, 0);
  }
  // C/D layout: col = lane&15, row = (lane>>4)*4 + reg   [m89-verified]
  int jo = lane & 15, io0 = (lane >> 4) * 4;
  #pragma unroll
  for (int r = 0; r < 4; ++r)
    atomicAdd(&sta[n*256 + (io0 + r)*16 + jo], acc[r]);
}

// ---- K5: normalize sta, emit (N,16,16,3) --------------------------------
__global__ void __launch_bounds__(256) k5_out(const float* __restrict__ sta,
                                              const unsigned* __restrict__ mn,
                                              const unsigned* __restrict__ mx,
                                              float* __restrict__ out){
  int n = blockIdx.x;                // grid 16 x 256
  int t = threadIdx.x;
  float s = sta[n*256 + t];
  float tot = wred_sum(s);
  __shared__ float sm[4];
  if ((t & 63) == 0) sm[t >> 6] = tot;
  __syncthreads();
  tot = (sm[0] + sm[1]) + (sm[2] + sm[3]);

  float cmin = unfl(mn[n]), cmax = unfl(mx[n]);
  float d = cmax - cmin;
  int i = t >> 4, j = t & 15;
  float qi = (float)(2*i + 1) * (1.0f/32.0f) * d + cmin;
  float qj = (float)(2*j + 1) * (1.0f/32.0f) * d + cmin;
  float* o = out + (size_t)(n*256 + t) * 3;
  o[0] = qj;        // qh[n,i,j] = q_levels[n,j]
  o[1] = qi;        // qw[n,i,j] = q_levels[n,i]
  o[2] = s / tot;   // normalized sta
}

// ---- launch --------------------------------------------------------------
extern "C" void kernel_launch(void* const* d_in, const int* in_sizes, int n_in,
                              void* d_out, int out_size, void* d_ws, size_t ws_size,
                              hipStream_t stream){
  const float4* xv = (const float4*)d_in[0];
  float* ws   = (float*)d_ws;
  float* sumc = ws + WS_SUMC;
  float* an   = ws + WS_AN;
  unsigned* mn = (unsigned*)ws + WS_MIN;
  unsigned* mx = (unsigned*)ws + WS_MAX;
  float* sta  = ws + WS_STA;
  float* cosb = ws + WS_COS;
  float* out  = (float*)d_out;

  k0_init <<<16,    256, 0, stream>>>(ws);
  k1_sums <<<16384, 256, 0, stream>>>(xv, sumc);
  k1b_norm<<<1,    1024, 0, stream>>>(sumc, an);
  k2_cos  <<<4096,  256, 0, stream>>>(xv, an, (float4*)cosb, mn, mx);
  k4_sta  <<<2048,  256, 0, stream>>>(cosb, mn, mx, sta);
  k5_out  <<<16,    256, 0, stream>>>(sta, mn, mx, out);
}

// Round 3
// 387.276 us; speedup vs baseline: 1.2067x; 1.2067x over previous
//
#include <hip/hip_runtime.h>
#include <hip/hip_bf16.h>

// Problem constants: x is (N=16, C=64, H=512, W=512) float32, LEVEL_NUM=16.
#define NB   16
#define CB   64
#define HH   512
#define WW   512
#define HWP  (HH*WW)          // 262144 pixels per (n,c)
#define HWP4 (HWP/4)          // 65536 float4 per (n,c)
#define LEV  16

typedef __attribute__((ext_vector_type(8))) short short8;
typedef __attribute__((ext_vector_type(4))) float f32x4;

// ---- helpers -------------------------------------------------------------

__device__ inline float wred_sum(float v){
  #pragma unroll
  for (int m = 32; m > 0; m >>= 1) v += __shfl_xor(v, m, 64);
  return v;
}
__device__ inline float wred_min(float v){
  #pragma unroll
  for (int m = 32; m > 0; m >>= 1) v = fminf(v, __shfl_xor(v, m, 64));
  return v;
}
__device__ inline float wred_max(float v){
  #pragma unroll
  for (int m = 32; m > 0; m >>= 1) v = fmaxf(v, __shfl_xor(v, m, 64));
  return v;
}

// monotonic float<->uint mapping so we can use atomicMin/Max on unsigned
__device__ inline unsigned fl(float f){
  unsigned b = __float_as_uint(f);
  return (b & 0x80000000u) ? ~b : (b | 0x80000000u);
}
__device__ inline float unfl(unsigned u){
  unsigned b = (u & 0x80000000u) ? (u ^ 0x80000000u) : ~u;
  return __uint_as_float(b);
}

// f32 -> bf16 bits, round-to-nearest-even (no NaN inputs here)
__device__ inline unsigned short f2bf(float f){
  unsigned u = __float_as_uint(f);
  unsigned r = (u + 0x7fffu + ((u >> 16) & 1u)) >> 16;
  return (unsigned short)r;
}

// ---- ws layout (float offsets) ------------------------------------------
#define WS_SUMC  0                       // 1024 per-(n,c) channel sums
#define WS_AN    1024                    // 1024 normalized x_ave
#define WS_MIN   2048                    // 16 uint (flipped)
#define WS_MAX   2064                    // 16 uint (flipped)
#define WS_COS   8192                    // 16*262144 cos map
#define WS_PARTS (WS_COS + NB*HWP)       // 16*32*256 sta partials

// ---- K1: per-(n,c) plane sums. One block per (n,c): 1 MB sequential. ----
__global__ void __launch_bounds__(256) k1_sums(const f32x4* __restrict__ xv,
                                               float* __restrict__ sumc){
  int nc = blockIdx.x;               // grid = 1024
  int t  = threadIdx.x;
  const f32x4* xb = xv + (size_t)nc * HWP4 + t;
  float s = 0.0f;
  #pragma unroll 8
  for (int k = 0; k < 256; ++k){
    f32x4 v = __builtin_nontemporal_load(xb + k*256);
    s += (v.x + v.y) + (v.z + v.w);
  }
  s = wred_sum(s);
  __shared__ float sm[4];
  if ((t & 63) == 0) sm[t >> 6] = s;
  __syncthreads();
  if (t == 0) sumc[nc] = (sm[0]+sm[1])+(sm[2]+sm[3]);
}

// ---- K1b: normalize x_ave (wave = one n) + init min/max accumulators ----
__global__ void __launch_bounds__(1024) k1b_norm(const float* __restrict__ sumc,
                                                 float* __restrict__ an,
                                                 unsigned* __restrict__ mn,
                                                 unsigned* __restrict__ mx){
  int t = threadIdx.x;               // 1 block x 1024; wave = one n
  if (t < 16){ mn[t] = 0xFFFFFFFFu; mx[t] = 0u; }
  float val = sumc[t] * (1.0f / (float)HWP);   // mean
  float s2 = wred_sum(val * val);
  float rn = 1.0f / fmaxf(sqrtf(s2), 1e-12f);
  an[t] = val * rn;
}

// ---- K2: cosine map + per-n min/max  (second 1 GiB read of x) -----------
// Block owns a 1024-float4 pixel chunk (4 float4/thread): per channel
// iteration it reads 16 KB contiguous before the 1 MB channel jump.
__global__ void __launch_bounds__(256) k2_cos(const f32x4* __restrict__ xv,
                                              const float* __restrict__ an,
                                              f32x4* __restrict__ cosv,
                                              unsigned* __restrict__ mn,
                                              unsigned* __restrict__ mx){
  int bid = blockIdx.x;              // grid = 16*64 = 1024
  int n = bid >> 6, ch = bid & 63;
  int t = threadIdx.x;
  int p0 = ch * 1024;
  __shared__ float sa[CB];
  if (t < CB) sa[t] = an[n*CB + t];
  __syncthreads();

  f32x4 dot[4], nrm[4];
  #pragma unroll
  for (int k = 0; k < 4; ++k){ dot[k] = (f32x4){0,0,0,0}; nrm[k] = (f32x4){0,0,0,0}; }

  const f32x4* xn = xv + (size_t)n * CB * HWP4 + p0 + t;
  #pragma unroll 2
  for (int c = 0; c < CB; ++c){
    const f32x4* xb = xn + (size_t)c * HWP4;
    float a = sa[c];
    #pragma unroll
    for (int k = 0; k < 4; ++k){
      f32x4 v = __builtin_nontemporal_load(xb + k*256);
      dot[k] += a * v;
      nrm[k] += v * v;
    }
  }

  float mnl =  2.0f, mxl = -2.0f;
  #pragma unroll
  for (int k = 0; k < 4; ++k){
    f32x4 cs;
    #pragma unroll
    for (int e = 0; e < 4; ++e){
      cs[e] = dot[k][e] / fmaxf(sqrtf(nrm[k][e]), 1e-12f);
      mnl = fminf(mnl, cs[e]); mxl = fmaxf(mxl, cs[e]);
    }
    cosv[(size_t)n * HWP4 + p0 + k*256 + t] = cs;
  }

  mnl = wred_min(mnl); mxl = wred_max(mxl);
  __shared__ float smn[4], smx[4];
  if ((t & 63) == 0){ smn[t >> 6] = mnl; smx[t >> 6] = mxl; }
  __syncthreads();
  if (t == 0){
    float m0 = fminf(fminf(smn[0], smn[1]), fminf(smn[2], smn[3]));
    float M0 = fmaxf(fmaxf(smx[0], smx[1]), fmaxf(smx[2], smx[3]));
    atomicMin(&mn[n], fl(m0));
    atomicMax(&mx[n], fl(M0));
  }
}

// ---- K4: soft-quant + co-occurrence via MFMA, atomic-free ---------------
// Wave owns 4 row-pairs, accumulates the 16x16 sta tile in AGPRs; the 4
// waves of a block LDS-reduce to one 256-float partial (no atomics).
__global__ void __launch_bounds__(256) k4_sta(const float* __restrict__ cosb,
                                              const unsigned* __restrict__ mn,
                                              const unsigned* __restrict__ mx,
                                              float* __restrict__ parts){
  int bid = blockIdx.x;              // grid = 16*32 = 512
  int n = bid >> 5, pb = bid & 31;
  int t = threadIdx.x;
  int wv = t >> 6, lane = t & 63;

  int lvl = lane & 15, g = lane >> 4;
  float cmin = unfl(mn[n]), cmax = unfl(mx[n]);
  float q = (float)(2*lvl + 1) * (1.0f/32.0f) * (cmax - cmin) + cmin;
  const float c3 = -0.022542110013890053f;   // -(sigma^2)*log2(e), sigma^2=1/64

  f32x4 acc = {0.f, 0.f, 0.f, 0.f};
  for (int rp = 0; rp < 4; ++rp){
    int h = pb*16 + wv*4 + rp;
    if (h > HH - 2) continue;        // valid row pairs: h in [0,510]
    const float* rowA = cosb + (size_t)n * HWP + (size_t)h * WW;
    const float* rowB = rowA + WW;
    #pragma unroll 4
    for (int kc = 0; kc < 16; ++kc){
      int px = kc*32 + g*8;
      float4 a0 = *(const float4*)(rowA + px);
      float4 a1 = *(const float4*)(rowA + px + 4);
      float4 b0 = *(const float4*)(rowB + px);
      float4 b1 = *(const float4*)(rowB + px + 4);
      float b8 = (px + 8 <= WW - 1) ? rowB[px + 8] : 0.0f;
      float av[8] = {a0.x,a0.y,a0.z,a0.w,a1.x,a1.y,a1.z,a1.w};
      float bv[8] = {b0.y,b0.z,b0.w,b1.x,b1.y,b1.z,b1.w,b8};
      short8 af, bf;
      #pragma unroll
      for (int e = 0; e < 8; ++e){
        float da = av[e] - q;  float pa = exp2f(c3*da*da);
        float db = bv[e] - q;  float pbv = exp2f(c3*db*db);
        if (px + e > WW - 2){ pa = 0.0f; pbv = 0.0f; }   // zero-pad border
        af[e] = (short)f2bf(pa);
        bf[e] = (short)f2bf(pbv);
      }
      acc = __builtin_amdgcn_mfma_f32_16x16x32_bf16(af, bf, acc, 0, 0, 0);
    }
  }
  // C/D layout: col = lane&15, row = (lane>>4)*4 + reg   [m89-verified]
  __shared__ float sm4[4][256];
  int jo = lane & 15, io0 = (lane >> 4) * 4;
  #pragma unroll
  for (int r = 0; r < 4; ++r) sm4[wv][(io0 + r)*16 + jo] = acc[r];
  __syncthreads();
  parts[(size_t)(n*32 + pb)*256 + t] =
      (sm4[0][t] + sm4[1][t]) + (sm4[2][t] + sm4[3][t]);
}

// ---- K5: reduce partials, normalize sta, emit (N,16,16,3) ---------------
__global__ void __launch_bounds__(256) k5_out(const float* __restrict__ parts,
                                              const unsigned* __restrict__ mn,
                                              const unsigned* __restrict__ mx,
                                              float* __restrict__ out){
  int n = blockIdx.x;                // grid 16 x 256
  int t = threadIdx.x;
  float s = 0.0f;
  #pragma unroll 8
  for (int pb = 0; pb < 32; ++pb) s += parts[(size_t)(n*32 + pb)*256 + t];

  float tot = wred_sum(s);
  __shared__ float sm[4];
  if ((t & 63) == 0) sm[t >> 6] = tot;
  __syncthreads();
  tot = (sm[0] + sm[1]) + (sm[2] + sm[3]);

  float cmin = unfl(mn[n]), cmax = unfl(mx[n]);
  float d = cmax - cmin;
  int i = t >> 4, j = t & 15;
  float qi = (float)(2*i + 1) * (1.0f/32.0f) * d + cmin;
  float qj = (float)(2*j + 1) * (1.0f/32.0f) * d + cmin;
  float* o = out + (size_t)(n*256 + t) * 3;
  o[0] = qj;        // qh[n,i,j] = q_levels[n,j]
  o[1] = qi;        // qw[n,i,j] = q_levels[n,i]
  o[2] = s / tot;   // normalized sta
}

// ---- launch --------------------------------------------------------------
extern "C" void kernel_launch(void* const* d_in, const int* in_sizes, int n_in,
                              void* d_out, int out_size, void* d_ws, size_t ws_size,
                              hipStream_t stream){
  const f32x4* xv = (const f32x4*)d_in[0];
  float* ws   = (float*)d_ws;
  float* sumc = ws + WS_SUMC;
  float* an   = ws + WS_AN;
  unsigned* mn = (unsigned*)ws + WS_MIN;
  unsigned* mx = (unsigned*)ws + WS_MAX;
  float* cosb = ws + WS_COS;
  float* parts= ws + WS_PARTS;
  float* out  = (float*)d_out;

  k1_sums <<<1024, 256, 0, stream>>>(xv, sumc);
  k1b_norm<<<1,   1024, 0, stream>>>(sumc, an, mn, mx);
  k2_cos  <<<1024, 256, 0, stream>>>(xv, an, (f32x4*)cosb, mn, mx);
  k4_sta  <<<512,  256, 0, stream>>>(cosb, mn, mx, parts);
  k5_out  <<<16,   256, 0, stream>>>(parts, mn, mx, out);
}

// Round 5
// 373.160 us; speedup vs baseline: 1.2524x; 1.0378x over previous
//
#include <hip/hip_runtime.h>
#include <hip/hip_bf16.h>

// Problem constants: x is (N=16, C=64, H=512, W=512) float32, LEVEL_NUM=16.
#define NB   16
#define CB   64
#define HH   512
#define WW   512
#define HWP  (HH*WW)          // 262144 pixels per (n,c)
#define HWP4 (HWP/4)          // 65536 float4 per (n,c)
#define LEV  16

typedef __attribute__((ext_vector_type(8))) short    short8;
typedef __attribute__((ext_vector_type(4))) float    f32x4;
typedef __attribute__((ext_vector_type(4))) unsigned u32x4;

// ---- helpers -------------------------------------------------------------

__device__ inline float wred_sum(float v){
  #pragma unroll
  for (int m = 32; m > 0; m >>= 1) v += __shfl_xor(v, m, 64);
  return v;
}
__device__ inline float wred_min(float v){
  #pragma unroll
  for (int m = 32; m > 0; m >>= 1) v = fminf(v, __shfl_xor(v, m, 64));
  return v;
}
__device__ inline float wred_max(float v){
  #pragma unroll
  for (int m = 32; m > 0; m >>= 1) v = fmaxf(v, __shfl_xor(v, m, 64));
  return v;
}

// monotonic float<->uint mapping so we can use atomicMin/Max on unsigned
__device__ inline unsigned fl(float f){
  unsigned b = __float_as_uint(f);
  return (b & 0x80000000u) ? ~b : (b | 0x80000000u);
}
__device__ inline float unfl(unsigned u){
  unsigned b = (u & 0x80000000u) ? (u ^ 0x80000000u) : ~u;
  return __uint_as_float(b);
}

#define C3 (-0.022542110013890053f)   // -(sigma^2)*log2(e), sigma^2 = 1/64

__device__ inline float qexp(float v, float q){
  float d = v - q; return exp2f(C3 * d * d);
}
// pack two f32 -> one u32 of 2x bf16 (RNE) via hardware v_cvt_pk_bf16_f32
__device__ inline unsigned pkbf(float a, float b){
  __hip_bfloat162 h = __float22bfloat162_rn(float2{a, b});
  unsigned u; __builtin_memcpy(&u, &h, sizeof(u));
  return u;
}

// ---- ws layout (float offsets) ------------------------------------------
#define WS_SUMC  0                       // 1024 per-(n,c) channel sums
#define WS_MIN   2048                    // 16 uint (flipped)
#define WS_MAX   2064                    // 16 uint (flipped)
#define WS_COS   8192                    // 16*262144 cos map
#define WS_PARTS (WS_COS + NB*HWP)       // 16*32*256 sta partials

// ---- K1: per-(n,c) plane sums (first 1 GiB read). Also inits mn/mx. -----
__global__ void __launch_bounds__(256) k1_sums(const f32x4* __restrict__ xv,
                                               float* __restrict__ sumc,
                                               unsigned* __restrict__ mn,
                                               unsigned* __restrict__ mx){
  int nc = blockIdx.x;               // grid = 1024, one block per (n,c) plane
  int t  = threadIdx.x;
  if ((nc & 63) == 0 && t == 0){     // first block of each n inits min/max;
    mn[nc >> 6] = 0xFFFFFFFFu;       // k1 fully completes before k2 reads.
    mx[nc >> 6] = 0u;
  }
  const f32x4* xb = xv + (size_t)nc * HWP4 + t;
  float s = 0.0f;
  #pragma unroll 8
  for (int k = 0; k < 256; ++k){
    f32x4 v = __builtin_nontemporal_load(xb + k*256);
    s += (v.x + v.y) + (v.z + v.w);
  }
  s = wred_sum(s);
  __shared__ float sm[4];
  if ((t & 63) == 0) sm[t >> 6] = s;
  __syncthreads();
  if (t == 0) sumc[nc] = (sm[0]+sm[1])+(sm[2]+sm[3]);
}

// ---- K2: cosine map + per-n min/max (second 1 GiB read) ----------------
// Fused: each block recomputes the normalized x_ave from sumc (cheap).
__global__ void __launch_bounds__(256) k2_cos(const f32x4* __restrict__ xv,
                                              const float* __restrict__ sumc,
                                              f32x4* __restrict__ cosv,
                                              unsigned* __restrict__ mn,
                                              unsigned* __restrict__ mx){
  int bid = blockIdx.x;              // grid = 16*64 = 1024
  int n = bid >> 6, ch = bid & 63;
  int t = threadIdx.x;
  int p0 = ch * 1024;
  __shared__ float sa[CB];
  if (t < CB){                       // wave 0 computes an[n, :] from sumc
    float val = sumc[n*CB + t] * (1.0f / (float)HWP);   // mean
    float s2 = wred_sum(val * val);
    sa[t] = val * (1.0f / fmaxf(sqrtf(s2), 1e-12f));
  }
  __syncthreads();

  f32x4 dot[4], nrm[4];
  #pragma unroll
  for (int k = 0; k < 4; ++k){ dot[k] = (f32x4){0,0,0,0}; nrm[k] = (f32x4){0,0,0,0}; }

  const f32x4* xn = xv + (size_t)n * CB * HWP4 + p0 + t;
  #pragma unroll 2
  for (int c = 0; c < CB; ++c){
    const f32x4* xb = xn + (size_t)c * HWP4;
    float a = sa[c];
    #pragma unroll
    for (int k = 0; k < 4; ++k){
      f32x4 v = __builtin_nontemporal_load(xb + k*256);
      dot[k] += a * v;
      nrm[k] += v * v;
    }
  }

  float mnl =  2.0f, mxl = -2.0f;
  #pragma unroll
  for (int k = 0; k < 4; ++k){
    f32x4 cs;
    #pragma unroll
    for (int e = 0; e < 4; ++e){
      cs[e] = dot[k][e] / fmaxf(sqrtf(nrm[k][e]), 1e-12f);
      mnl = fminf(mnl, cs[e]); mxl = fmaxf(mxl, cs[e]);
    }
    cosv[(size_t)n * HWP4 + p0 + k*256 + t] = cs;
  }

  mnl = wred_min(mnl); mxl = wred_max(mxl);
  __shared__ float smn[4], smx[4];
  if ((t & 63) == 0){ smn[t >> 6] = mnl; smx[t >> 6] = mxl; }
  __syncthreads();
  if (t == 0){
    float m0 = fminf(fminf(smn[0], smn[1]), fminf(smn[2], smn[3]));
    float M0 = fmaxf(fmaxf(smx[0], smx[1]), fmaxf(smx[2], smx[3]));
    atomicMin(&mn[n], fl(m0));
    atomicMax(&mx[n], fl(M0));
  }
}

// ---- K4: soft-quant + co-occurrence via MFMA, atomic-free ---------------
// Wave owns 4 row-pairs (rows h0..h0+4). Per 32-pixel chunk it computes the
// quant levels of each of the 5 rows ONCE (8 + 1 shifted-border evals per
// row), reuses them as A (rows r) and 1-pixel-shifted B (rows r+1) via
// packed 16-bit shifts. All 4 pairs accumulate into one 16x16 AGPR tile;
// the block's 4 waves LDS-reduce to a 256-float partial (no atomics).
__global__ void __launch_bounds__(256) k4_sta(const float* __restrict__ cosb,
                                              const unsigned* __restrict__ mn,
                                              const unsigned* __restrict__ mx,
                                              float* __restrict__ parts){
  int bid = blockIdx.x;              // grid = 16*32 = 512
  int n = bid >> 5, pb = bid & 31;
  int t = threadIdx.x;
  int wv = t >> 6, lane = t & 63;
  int lvl = lane & 15, g = lane >> 4;

  float cmin = unfl(mn[n]), cmax = unfl(mx[n]);
  float q = (float)(2*lvl + 1) * (1.0f/32.0f) * (cmax - cmin) + cmin;
  int h0 = pb*16 + wv*4;
  const float* cosn = cosb + (size_t)n * HWP;

  f32x4 acc = {0.f, 0.f, 0.f, 0.f};
  #pragma unroll 2
  for (int kc = 0; kc < 16; ++kc){
    int px = kc*32 + g*8;
    unsigned qp[5][4];               // 5 rows x 8 quants as packed bf16
    unsigned qx[5];                  // quant of pixel px+8 (bf16 in low 16)
    bool in8 = (px + 8 <= WW - 1);
    #pragma unroll
    for (int r = 0; r < 5; ++r){
      int hr = h0 + r; if (hr > HH - 1) hr = HH - 1;   // clamp: value unused
      const float* row = cosn + (size_t)hr * WW + px;
      float4 v0 = *(const float4*)row;
      float4 v1 = *(const float4*)(row + 4);
      qp[r][0] = pkbf(qexp(v0.x,q), qexp(v0.y,q));
      qp[r][1] = pkbf(qexp(v0.z,q), qexp(v0.w,q));
      qp[r][2] = pkbf(qexp(v1.x,q), qexp(v1.y,q));
      qp[r][3] = pkbf(qexp(v1.z,q), qexp(v1.w,q));
      float p8 = in8 ? qexp(row[8], q) : 0.0f;  // zero-pad at source pixel 512
      qx[r] = pkbf(p8, 0.0f);
    }
    #pragma unroll
    for (int r = 0; r < 4; ++r){
      if (h0 + r <= HH - 2){         // wave-uniform; pair (511,512) invalid
        u32x4 aw = {qp[r][0], qp[r][1], qp[r][2], qp[r][3]};
        // B = row r+1 shifted left one pixel: elems (1..7, px+8)
        u32x4 bw = {(qp[r+1][0] >> 16) | (qp[r+1][1] << 16),
                    (qp[r+1][1] >> 16) | (qp[r+1][2] << 16),
                    (qp[r+1][2] >> 16) | (qp[r+1][3] << 16),
                    (qp[r+1][3] >> 16) | (qx[r+1]    << 16)};
        acc = __builtin_amdgcn_mfma_f32_16x16x32_bf16(
                __builtin_bit_cast(short8, aw),
                __builtin_bit_cast(short8, bw), acc, 0, 0, 0);
      }
    }
  }
  // C/D layout: col = lane&15, row = (lane>>4)*4 + reg   [m89-verified]
  __shared__ float sm4[4][256];
  int jo = lane & 15, io0 = (lane >> 4) * 4;
  #pragma unroll
  for (int r = 0; r < 4; ++r) sm4[wv][(io0 + r)*16 + jo] = acc[r];
  __syncthreads();
  parts[(size_t)(n*32 + pb)*256 + t] =
      (sm4[0][t] + sm4[1][t]) + (sm4[2][t] + sm4[3][t]);
}

// ---- K5: reduce partials, normalize sta, emit (N,16,16,3) ---------------
__global__ void __launch_bounds__(256) k5_out(const float* __restrict__ parts,
                                              const unsigned* __restrict__ mn,
                                              const unsigned* __restrict__ mx,
                                              float* __restrict__ out){
  int n = blockIdx.x;                // grid 16 x 256
  int t = threadIdx.x;
  float s = 0.0f;
  #pragma unroll 8
  for (int pb = 0; pb < 32; ++pb) s += parts[(size_t)(n*32 + pb)*256 + t];

  float tot = wred_sum(s);
  __shared__ float sm[4];
  if ((t & 63) == 0) sm[t >> 6] = tot;
  __syncthreads();
  tot = (sm[0] + sm[1]) + (sm[2] + sm[3]);

  float cmin = unfl(mn[n]), cmax = unfl(mx[n]);
  float d = cmax - cmin;
  int i = t >> 4, j = t & 15;
  float qi = (float)(2*i + 1) * (1.0f/32.0f) * d + cmin;
  float qj = (float)(2*j + 1) * (1.0f/32.0f) * d + cmin;
  float* o = out + (size_t)(n*256 + t) * 3;
  o[0] = qj;        // qh[n,i,j] = q_levels[n,j]
  o[1] = qi;        // qw[n,i,j] = q_levels[n,i]
  o[2] = s / tot;   // normalized sta
}

// ---- launch --------------------------------------------------------------
extern "C" void kernel_launch(void* const* d_in, const int* in_sizes, int n_in,
                              void* d_out, int out_size, void* d_ws, size_t ws_size,
                              hipStream_t stream){
  const f32x4* xv = (const f32x4*)d_in[0];
  float* ws   = (float*)d_ws;
  float* sumc = ws + WS_SUMC;
  unsigned* mn = (unsigned*)ws + WS_MIN;
  unsigned* mx = (unsigned*)ws + WS_MAX;
  float* cosb = ws + WS_COS;
  float* parts= ws + WS_PARTS;
  float* out  = (float*)d_out;

  k1_sums <<<1024, 256, 0, stream>>>(xv, sumc, mn, mx);
  k2_cos  <<<1024, 256, 0, stream>>>(xv, sumc, (f32x4*)cosb, mn, mx);
  k4_sta  <<<512,  256, 0, stream>>>(cosb, mn, mx, parts);
  k5_out  <<<16,   256, 0, stream>>>(parts, mn, mx, out);
}